// Round 10
// baseline (64.781 us; speedup 1.0000x reference)
//
#include <hip/hip_runtime.h>
#include <hip/hip_bf16.h>

typedef __bf16 bf16x8 __attribute__((ext_vector_type(8)));
typedef __bf16 bf16x4 __attribute__((ext_vector_type(4)));
typedef float  f32x4  __attribute__((ext_vector_type(4)));

constexpr int kD  = 512;
constexpr int kBD = 64;
constexpr int kN  = 4096;
constexpr int kB  = 8;

constexpr int BROWS = 32;   // rows per block -> grid 1024 (4 blocks/CU)
constexpr int NPH   = 8;    // d-units of 64 floats (staged 32r x 64d x {K,V} = 16 KB/phase)

typedef const __attribute__((address_space(1))) void* gas_t;
typedef __attribute__((address_space(3))) void*       las_t;

static __device__ __forceinline__ void gload16(const void* g, void* l) {
    __builtin_amdgcn_global_load_lds((gas_t)g, (las_t)l, 16, 0, 0);
}

__device__ __forceinline__ bf16x8 cvt8(float4 a, float4 b) {
    bf16x8 r;
    r[0] = (__bf16)a.x; r[1] = (__bf16)a.y; r[2] = (__bf16)a.z; r[3] = (__bf16)a.w;
    r[4] = (__bf16)b.x; r[5] = (__bf16)b.y; r[6] = (__bf16)b.z; r[7] = (__bf16)b.w;
    return r;
}

// PROBE: m13-faithful pure read of keys (67 MB). Measures the achievable
// read rate for THIS data in THIS cache state, decoupled from any MFMA/LDS
// consumption. Result -> ws scratch (deterministic, unused by output).
__global__ __launch_bounds__(256)
void lbm_probe(const float* __restrict__ keys, float* __restrict__ po)
{
    const size_t idx    = (size_t)blockIdx.x * 256 + threadIdx.x;
    const size_t stride = (size_t)gridDim.x * 256;
    const float4* k4 = (const float4*)keys;
    const size_t n4 = (size_t)kB * kN * kD / 4;   // 4.19M float4
    float acc = 0.f;
    for (size_t i = idx; i < n4; i += stride) {
        float4 a = k4[i];
        acc += a.x + a.y + a.z + a.w;
    }
    #pragma unroll
    for (int m = 1; m < 64; m <<= 1) acc += __shfl_xor(acc, m);
    __shared__ float r[4];
    if ((threadIdx.x & 63) == 0) r[threadIdx.x >> 6] = acc;
    __syncthreads();
    if (threadIdx.x == 0) po[blockIdx.x] = r[0] + r[1] + r[2] + r[3];
}

// Prep: Wbk/Wbv fp32 -> bf16 ws images (blocks 0..31); block 32 zeroes S.
__global__ __launch_bounds__(256)
void lbm_prep(const float* __restrict__ Wbk, const float* __restrict__ Wbv,
              __bf16* __restrict__ wsk, __bf16* __restrict__ wsv,
              float* __restrict__ S)
{
    const int bid = blockIdx.x, t = threadIdx.x;
    if (bid < 32) {
        int i = (bid * 256 + t) * 4;
        float4 a = *(const float4*)(Wbk + i);
        float4 b = *(const float4*)(Wbv + i);
        bf16x4 ka, vb;
        ka[0]=(__bf16)a.x; ka[1]=(__bf16)a.y; ka[2]=(__bf16)a.z; ka[3]=(__bf16)a.w;
        vb[0]=(__bf16)b.x; vb[1]=(__bf16)b.y; vb[2]=(__bf16)b.z; vb[3]=(__bf16)b.w;
        *(bf16x4*)(wsk + i) = ka;
        *(bf16x4*)(wsv + i) = vb;
    } else {
        S[t * 2] = 0.f; S[t * 2 + 1] = 0.f;
    }
}

// S[b,j] = sum_n (keys[b,n,:].Wbk[j,:] + bbk[j]) * (values[b,n,:].Wbv[j,:] + bbv[j])
// (byte-identical to round 9 -- probe is the only change this round)
__global__ __launch_bounds__(256, 4)
void lbm_bind(const float* __restrict__ keys, const float* __restrict__ values,
              const __bf16* __restrict__ wsk, const __bf16* __restrict__ wsv,
              const float* __restrict__ bbk,  const float* __restrict__ bbv,
              float* __restrict__ S)
{
    __shared__ float lds[2][2][16 * 128];   // [buf][K/V][32r x 64d as 16x128] = 32 KB

    const int tid = threadIdx.x;
    const int wv  = tid >> 6;
    const int ln  = tid & 63;
    const int l15 = ln & 15;
    const int lhi = ln >> 4;
    const int jrow = wv * 16 + l15;      // weight row (j) for B-operand
    const int dk   = lhi * 8;

    // XCD-aware bijective swizzle (nwg=1024, 8 XCDs -> 128 contiguous blocks/XCD)
    const int bid = blockIdx.x;
    const int swzb = (bid & 7) * 128 + (bid >> 3);
    const int blockRow0 = swzb * BROWS;

#define STAGE(p)                                                              \
    {                                                                         \
        _Pragma("unroll")                                                     \
        for (int i_ = 0; i_ < 2; ++i_) {                                      \
            int g_  = i_ * 256 + tid;      /* granule 0..511 */               \
            int r_  = g_ >> 4;             /* row 0..31 */                    \
            int gl_ = g_ & 15;             /* dest granule col in 64d run */  \
            int gs_ = gl_ ^ (r_ & 7);      /* swizzled source granule */      \
            size_t so_ = (size_t)(blockRow0 + r_) * kD + (p) * 64 + gs_ * 4;  \
            gload16(keys   + so_, &lds[(p) & 1][0][g_ * 4]);                  \
            gload16(values + so_, &lds[(p) & 1][1][g_ * 4]);                  \
        }                                                                     \
    }

    STAGE(0)

    // ---- resident weight frags for d-units 0..3 (16 frags = 64 VGPR) ----
    bf16x8 wrk[4][2], wrv[4][2];
    #pragma unroll
    for (int u = 0; u < 4; ++u) {
        wrk[u][0] = *(const bf16x8*)(wsk + jrow * kD + u * 64 + dk);
        wrk[u][1] = *(const bf16x8*)(wsk + jrow * kD + u * 64 + 32 + dk);
        wrv[u][0] = *(const bf16x8*)(wsv + jrow * kD + u * 64 + dk);
        wrv[u][1] = *(const bf16x8*)(wsv + jrow * kD + u * 64 + 32 + dk);
    }
    #pragma unroll
    for (int u = 0; u < 4; ++u) {
        asm volatile("" : "+v"(wrk[u][0]), "+v"(wrk[u][1]),
                          "+v"(wrv[u][0]), "+v"(wrv[u][1]));
    }
    const float bk = bbk[jrow];
    const float bv = bbv[jrow];

    __syncthreads();   // unit 0 resident

    f32x4 kacc[2] = {{0.f,0.f,0.f,0.f},{0.f,0.f,0.f,0.f}};
    f32x4 vacc[2] = {{0.f,0.f,0.f,0.f},{0.f,0.f,0.f,0.f}};

    #pragma unroll
    for (int p = 0; p < NPH; ++p) {
        if (p + 1 < NPH) STAGE(p + 1)

        const int buf = p & 1;

        bf16x8 wk0, wk1, wv0, wv1;
        if (p < 4) {
            wk0 = wrk[p][0]; wk1 = wrk[p][1];
            wv0 = wrv[p][0]; wv1 = wrv[p][1];
        } else {
            wk0 = *(const bf16x8*)(wsk + jrow * kD + p * 64 + dk);
            wk1 = *(const bf16x8*)(wsk + jrow * kD + p * 64 + 32 + dk);
            wv0 = *(const bf16x8*)(wsv + jrow * kD + p * 64 + dk);
            wv1 = *(const bf16x8*)(wsv + jrow * kD + p * 64 + 32 + dk);
        }

        #pragma unroll
        for (int ch = 0; ch < 2; ++ch) {
            const int rowA = ch * 16 + l15;
            const int swr  = rowA & 7;
            const float* bK = &lds[buf][0][0];
            const float* bV = &lds[buf][1][0];

            const int gc0 = lhi * 2;
            const int o00 = rowA * 64 + ((gc0 ^ swr) << 2);
            const int o01 = rowA * 64 + (((gc0 + 1) ^ swr) << 2);
            const int gc1 = 8 + lhi * 2;
            const int o10 = rowA * 64 + ((gc1 ^ swr) << 2);
            const int o11 = rowA * 64 + (((gc1 + 1) ^ swr) << 2);

            float4 a, b;
            a = *(const float4*)&bK[o00]; b = *(const float4*)&bK[o01];
            kacc[ch] = __builtin_amdgcn_mfma_f32_16x16x32_bf16(cvt8(a, b), wk0, kacc[ch], 0, 0, 0);
            a = *(const float4*)&bV[o00]; b = *(const float4*)&bV[o01];
            vacc[ch] = __builtin_amdgcn_mfma_f32_16x16x32_bf16(cvt8(a, b), wv0, vacc[ch], 0, 0, 0);
            a = *(const float4*)&bK[o10]; b = *(const float4*)&bK[o11];
            kacc[ch] = __builtin_amdgcn_mfma_f32_16x16x32_bf16(cvt8(a, b), wk1, kacc[ch], 0, 0, 0);
            a = *(const float4*)&bV[o10]; b = *(const float4*)&bV[o11];
            vacc[ch] = __builtin_amdgcn_mfma_f32_16x16x32_bf16(cvt8(a, b), wv1, vacc[ch], 0, 0, 0);
        }

        __syncthreads();
    }
#undef STAGE

    float sreg = 0.0f;
    #pragma unroll
    for (int ch = 0; ch < 2; ++ch)
        #pragma unroll
        for (int i = 0; i < 4; ++i)
            sreg += (kacc[ch][i] + bk) * (vacc[ch][i] + bv);

    sreg += __shfl_xor(sreg, 16);
    sreg += __shfl_xor(sreg, 32);
    if (lhi == 0) {
        int bidx = blockRow0 >> 12;   // / kN
        atomicAdd(&S[bidx * kBD + jrow], sreg);
    }
}

// Fused tail: 64 blocks; each block redundantly computes S->Bsum->ms->ext->LN
// for its batch b (tiny), then produces its 64-wide slice of out = normed.Wo^T + bo.
__global__ __launch_bounds__(256)
void lbm_tail(const float* __restrict__ S,    const float* __restrict__ query,
              const float* __restrict__ Wbc,  const float* __restrict__ bbc,
              const float* __restrict__ Wuq,  const float* __restrict__ buq,
              const float* __restrict__ Wue,  const float* __restrict__ bue,
              const float* __restrict__ ln_g, const float* __restrict__ ln_b,
              const float* __restrict__ Wo,   const float* __restrict__ bo,
              float* __restrict__ out)
{
    const int b = blockIdx.x >> 3;
    const int s = blockIdx.x & 7;          // 64-wide output slice
    const int t = threadIdx.x;

    __shared__ float shS[kBD];
    __shared__ float shB[kD];
    __shared__ float shMs[kBD];
    __shared__ float shN[kD];
    __shared__ float redT[4][kBD];
    __shared__ float redQ[4][kBD];
    __shared__ float redLN[8];
    __shared__ float s_mu, s_rs;

    if (t < kBD) shS[t] = S[b * kBD + t];
    __syncthreads();

    // Bsum[d] = sum_j S[j]*Wbc[d,j] + n*bbc[d]
    for (int d = t; d < kD; d += 256) {
        const float4* wr = (const float4*)(Wbc + d * kBD);
        float acc = 0.f;
        #pragma unroll
        for (int q4 = 0; q4 < 16; ++q4) {
            float4 w = wr[q4];
            acc += w.x * shS[q4*4+0] + w.y * shS[q4*4+1]
                 + w.z * shS[q4*4+2] + w.w * shS[q4*4+3];
        }
        shB[d] = acc + (float)kN * bbc[d];
    }
    __syncthreads();

    // t[jj] = Bsum.Wuq[jj,:] + n*buq ; q[jj] = query.Wuq[jj,:] + buq ; ms = q*t
    {
        const int jj = t & 63, qq = t >> 6;
        const float4* wr = (const float4*)(Wuq + jj * kD + qq * 128);
        const float4* qr = (const float4*)(query + b * kD + qq * 128);
        const float4* br = (const float4*)(shB + qq * 128);
        float at = 0.f, aq = 0.f;
        #pragma unroll
        for (int i = 0; i < 32; ++i) {
            float4 w = wr[i]; float4 bb = br[i]; float4 qv = qr[i];
            at += w.x*bb.x + w.y*bb.y + w.z*bb.z + w.w*bb.w;
            aq += w.x*qv.x + w.y*qv.y + w.z*qv.z + w.w*qv.w;
        }
        redT[qq][jj] = at; redQ[qq][jj] = aq;
    }
    __syncthreads();
    if (t < kBD) {
        float tv = redT[0][t] + redT[1][t] + redT[2][t] + redT[3][t] + (float)kN * buq[t];
        float qv = redQ[0][t] + redQ[1][t] + redQ[2][t] + redQ[3][t] + buq[t];
        shMs[t] = tv * qv;
    }
    __syncthreads();

    // ext[d] -> ret -> LN stats
    float lsum = 0.f, lsq = 0.f;
    for (int d = t; d < kD; d += 256) {
        const float4* wr = (const float4*)(Wue + d * kBD);
        float acc = 0.f;
        #pragma unroll
        for (int q4 = 0; q4 < 16; ++q4) {
            float4 w = wr[q4];
            acc += w.x * shMs[q4*4+0] + w.y * shMs[q4*4+1]
                 + w.z * shMs[q4*4+2] + w.w * shMs[q4*4+3];
        }
        float ret = (acc + (float)kN * bue[d]) * (1.0f / 64.0f);
        shN[d] = ret;
        lsum += ret; lsq += ret * ret;
    }
    #pragma unroll
    for (int m = 1; m < 64; m <<= 1) {
        lsum += __shfl_xor(lsum, m);
        lsq  += __shfl_xor(lsq, m);
    }
    if ((t & 63) == 0) { redLN[t >> 6] = lsum; redLN[4 + (t >> 6)] = lsq; }
    __syncthreads();
    if (t == 0) {
        float s0 = redLN[0] + redLN[1] + redLN[2] + redLN[3];
        float s1 = redLN[4] + redLN[5] + redLN[6] + redLN[7];
        float mu = s0 / (float)kD;
        float var = s1 / (float)kD - mu * mu;
        s_mu = mu;
        s_rs = rsqrtf(var + 1e-5f);
    }
    __syncthreads();
    {
        float mu = s_mu, rs = s_rs;
        for (int d = t; d < kD; d += 256)
            shN[d] = (shN[d] - mu) * rs * ln_g[d] + ln_b[d];
    }
    __syncthreads();

    // out slice: d = s*64 + t/4, quarter q = t&3 over the 512-dot
    {
        const int d = s * 64 + (t >> 2);
        const int q = t & 3;
        const float4* wr = (const float4*)(Wo + d * kD + q * 128);
        const float4* nr = (const float4*)(shN + q * 128);
        float acc = 0.f;
        #pragma unroll
        for (int i = 0; i < 32; ++i) {
            float4 w = wr[i]; float4 nv = nr[i];
            acc += w.x*nv.x + w.y*nv.y + w.z*nv.z + w.w*nv.w;
        }
        acc += __shfl_xor(acc, 1);
        acc += __shfl_xor(acc, 2);
        if (q == 0) out[b * kD + d] = acc + bo[d];
    }
}

extern "C" void kernel_launch(void* const* d_in, const int* in_sizes, int n_in,
                              void* d_out, int out_size, void* d_ws, size_t ws_size,
                              hipStream_t stream) {
    const float* keys   = (const float*)d_in[0];
    const float* values = (const float*)d_in[1];
    const float* query  = (const float*)d_in[2];
    const float* Wbk    = (const float*)d_in[3];
    const float* bbk    = (const float*)d_in[4];
    const float* Wbv    = (const float*)d_in[5];
    const float* bbv    = (const float*)d_in[6];
    const float* Wbc    = (const float*)d_in[7];
    const float* bbc    = (const float*)d_in[8];
    const float* Wuq    = (const float*)d_in[9];
    const float* buq    = (const float*)d_in[10];
    const float* Wue    = (const float*)d_in[11];
    const float* bue    = (const float*)d_in[12];
    const float* ln_g   = (const float*)d_in[13];
    const float* ln_b   = (const float*)d_in[14];
    const float* Wo     = (const float*)d_in[15];
    const float* bo     = (const float*)d_in[16];

    // ws layout: S[8][64] f32 (2 KB), wsk (64 KB), wsv (64 KB), probe out (8 KB)
    float*  Sacc = (float*)d_ws;
    __bf16* wsk  = (__bf16*)((char*)d_ws + 2048);
    __bf16* wsv  = wsk + kBD * kD;
    float*  pout = (float*)((char*)d_ws + 2048 + 2 * kBD * kD * sizeof(__bf16));
    float*  out  = (float*)d_out;

    // PROBE: pure-read rate measurement on keys (67 MB), m13 pattern.
    lbm_probe<<<dim3(2048), dim3(256), 0, stream>>>(keys, pout);

    lbm_prep<<<dim3(33), dim3(256), 0, stream>>>(Wbk, Wbv, wsk, wsv, Sacc);

    const int nblocks = (kB * kN) / BROWS;   // 1024 -> 4 blocks/CU
    lbm_bind<<<dim3(nblocks), dim3(256), 0, stream>>>(keys, values, wsk, wsv, bbk, bbv, Sacc);
    lbm_tail<<<dim3(kB * 8), dim3(256), 0, stream>>>(Sacc, query, Wbc, bbc, Wuq, buq,
                                                     Wue, bue, ln_g, ln_b, Wo, bo, out);
}

// Round 11
// 54.240 us; speedup vs baseline: 1.1943x; 1.1943x over previous
//
#include <hip/hip_runtime.h>
#include <hip/hip_bf16.h>

typedef __bf16 bf16x8 __attribute__((ext_vector_type(8)));
typedef __bf16 bf16x4 __attribute__((ext_vector_type(4)));
typedef float  f32x4  __attribute__((ext_vector_type(4)));

constexpr int kD  = 512;
constexpr int kBD = 64;
constexpr int kN  = 4096;
constexpr int kB  = 8;

__device__ __forceinline__ bf16x8 cvt8v(f32x4 a, f32x4 b) {
    bf16x8 r;
    r[0] = (__bf16)a[0]; r[1] = (__bf16)a[1]; r[2] = (__bf16)a[2]; r[3] = (__bf16)a[3];
    r[4] = (__bf16)b[0]; r[5] = (__bf16)b[1]; r[6] = (__bf16)b[2]; r[7] = (__bf16)b[3];
    return r;
}

// Prep: Wbk/Wbv fp32 -> bf16 ws images (blocks 0..31); block 32 zeroes S.
__global__ __launch_bounds__(256)
void lbm_prep(const float* __restrict__ Wbk, const float* __restrict__ Wbv,
              __bf16* __restrict__ wsk, __bf16* __restrict__ wsv,
              float* __restrict__ S)
{
    const int bid = blockIdx.x, t = threadIdx.x;
    if (bid < 32) {
        int i = (bid * 256 + t) * 4;
        float4 a = *(const float4*)(Wbk + i);
        float4 b = *(const float4*)(Wbv + i);
        bf16x4 ka, vb;
        ka[0]=(__bf16)a.x; ka[1]=(__bf16)a.y; ka[2]=(__bf16)a.z; ka[3]=(__bf16)a.w;
        vb[0]=(__bf16)b.x; vb[1]=(__bf16)b.y; vb[2]=(__bf16)b.z; vb[3]=(__bf16)b.w;
        *(bf16x4*)(wsk + i) = ka;
        *(bf16x4*)(wsv + i) = vb;
    } else {
        S[t * 2] = 0.f; S[t * 2 + 1] = 0.f;
    }
}

// S[b,j] = sum_n (keys[b,n,:].Wbk[j,:] + bbk[j]) * (values[b,n,:].Wbv[j,:] + bbv[j])
//
// Inverted structure (R10 probe: pure read >= 7 TB/s, gload_lds-DMA caps at
// ~11 GB/s/CU): ALL weights live in LDS (128 KB, XOR-swizzled, staged once);
// data streams global->reg->MFMA on the proven register path. 8 waves/block,
// each wave owns a private 16-row chunk (zero redundancy) and computes all
// 64 j via 8 MFMAs/step against the shared LDS weights. No main-loop barriers;
// 4-slot counted-vmcnt pipeline. 256 blocks (1/CU); XCD swizzle: 1 batch/XCD.
__global__ __launch_bounds__(512, 2)
void lbm_bind(const float* __restrict__ keys, const float* __restrict__ values,
              const __bf16* __restrict__ wsk, const __bf16* __restrict__ wsv,
              const float* __restrict__ bbk,  const float* __restrict__ bbv,
              float* __restrict__ S)
{
    __shared__ __bf16 ldsW[2][kBD * kD];   // [K/V][64 j][512 d] swizzled = 128 KB

    const int tid = threadIdx.x;
    const int w   = tid >> 6;
    const int ln  = tid & 63;
    const int l15 = ln & 15;
    const int lhi = ln >> 4;
    const int sw7 = l15 & 7;

    // XCD-aware bijective swizzle: 256 blocks, 8 XCDs -> 32 contiguous each
    const int bid  = blockIdx.x;
    const int swzb = (bid & 7) * 32 + (bid >> 3);
    const int blockRow0 = swzb * 128;
    const int row0 = blockRow0 + w * 16;       // this wave's private 16 rows

    // ---- data stream bases (A-frag: row = l15, k-offset = lhi*8) ----
    const float* kbase = keys   + (size_t)(row0 + l15) * kD + lhi * 8;
    const float* vbase = values + (size_t)(row0 + l15) * kD + lhi * 8;

#define GLD2X(ra, rb, base_, off_)                                            \
    asm volatile("global_load_dwordx4 %0, %2, off offset:%c3\n\t"             \
                 "global_load_dwordx4 %1, %2, off offset:%c4"                 \
                 : "=v"(ra), "=v"(rb)                                         \
                 : "v"(base_), "i"(off_), "i"((off_) + 16));
#define WAITN(n_, r0, r1, r2, r3)                                             \
    asm volatile("s_waitcnt vmcnt(%c4)"                                       \
                 : "+v"(r0), "+v"(r1), "+v"(r2), "+v"(r3) : "i"(n_));

    f32x4 ka[4], kb2[4], va[4], vb2[4];
    // prologue: 4 slots (16 loads, 16 KB/wave) in flight under weight staging
    GLD2X(ka[0], kb2[0], kbase,   0) GLD2X(va[0], vb2[0], vbase,   0)
    GLD2X(ka[1], kb2[1], kbase, 128) GLD2X(va[1], vb2[1], vbase, 128)
    GLD2X(ka[2], kb2[2], kbase, 256) GLD2X(va[2], vb2[2], vbase, 256)
    GLD2X(ka[3], kb2[3], kbase, 384) GLD2X(va[3], vb2[3], vbase, 384)

    // ---- stage both weight images into swizzled LDS (once per block) ----
    // granule c (16B) of row j stored at c ^ (j&7): conflict-light frag reads.
    #pragma unroll
    for (int i = 0; i < 8; ++i) {
        int G = i * 512 + tid;                 // granule 0..4095
        int j = G >> 6, c = G & 63;
        int dst = j * kD + ((c ^ (j & 7)) << 3);
        *(bf16x8*)&ldsW[0][dst] = *(const bf16x8*)(wsk + G * 8);
        *(bf16x8*)&ldsW[1][dst] = *(const bf16x8*)(wsv + G * 8);
    }

    // biases for the 4 j-tiles
    float bk[4], bv[4];
    #pragma unroll
    for (int jt = 0; jt < 4; ++jt) {
        bk[jt] = bbk[jt * 16 + l15];
        bv[jt] = bbv[jt * 16 + l15];
    }

    __syncthreads();   // weights resident

    f32x4 kacc[4], vacc[4];
    #pragma unroll
    for (int jt = 0; jt < 4; ++jt) {
        kacc[jt][0]=0.f; kacc[jt][1]=0.f; kacc[jt][2]=0.f; kacc[jt][3]=0.f;
        vacc[jt][0]=0.f; vacc[jt][1]=0.f; vacc[jt][2]=0.f; vacc[jt][3]=0.f;
    }

    // step s: d-range [s*32, s*32+32); slot = s&3; no barriers, counted vmcnt.
#define STEP(s_, n_)                                                          \
    {                                                                         \
        WAITN(n_, ka[(s_) & 3], kb2[(s_) & 3], va[(s_) & 3], vb2[(s_) & 3])   \
        bf16x8 ak_ = cvt8v(ka[(s_) & 3], kb2[(s_) & 3]);                      \
        bf16x8 av_ = cvt8v(va[(s_) & 3], vb2[(s_) & 3]);                      \
        if ((s_) + 4 < 16) {                                                  \
            GLD2X(ka[(s_) & 3], kb2[(s_) & 3], kbase, ((s_) + 4) * 128)       \
            GLD2X(va[(s_) & 3], vb2[(s_) & 3], vbase, ((s_) + 4) * 128)       \
        }                                                                     \
        const int go_ = (((s_) * 4 + lhi) ^ sw7) << 3;                        \
        _Pragma("unroll")                                                     \
        for (int jt = 0; jt < 4; ++jt) {                                      \
            bf16x8 fk_ = *(const bf16x8*)&ldsW[0][(jt * 16 + l15) * kD + go_];\
            bf16x8 fv_ = *(const bf16x8*)&ldsW[1][(jt * 16 + l15) * kD + go_];\
            kacc[jt] = __builtin_amdgcn_mfma_f32_16x16x32_bf16(ak_, fk_, kacc[jt], 0, 0, 0); \
            vacc[jt] = __builtin_amdgcn_mfma_f32_16x16x32_bf16(av_, fv_, vacc[jt], 0, 0, 0); \
        }                                                                     \
    }

    STEP(0, 12)  STEP(1, 12)  STEP(2, 12)  STEP(3, 12)
    STEP(4, 12)  STEP(5, 12)  STEP(6, 12)  STEP(7, 12)
    STEP(8, 12)  STEP(9, 12)  STEP(10, 12) STEP(11, 12)
    STEP(12, 12) STEP(13, 8)  STEP(14, 4)  STEP(15, 0)
#undef STEP
#undef WAITN
#undef GLD2X

    // combine: lane holds C col j = jt*16+l15, rows (lhi*4+i) -- rows sum away
    #pragma unroll
    for (int jt = 0; jt < 4; ++jt) {
        float sreg = 0.0f;
        #pragma unroll
        for (int i = 0; i < 4; ++i)
            sreg += (kacc[jt][i] + bk[jt]) * (vacc[jt][i] + bv[jt]);
        sreg += __shfl_xor(sreg, 16);
        sreg += __shfl_xor(sreg, 32);
        if (lhi == 0) {
            int bidx = blockRow0 >> 12;   // / kN
            atomicAdd(&S[bidx * kBD + jt * 16 + l15], sreg);
        }
    }
}

// Fused tail: 64 blocks; each block redundantly computes S->Bsum->ms->ext->LN
// for its batch b (tiny), then produces its 64-wide slice of out = normed.Wo^T + bo.
__global__ __launch_bounds__(256)
void lbm_tail(const float* __restrict__ S,    const float* __restrict__ query,
              const float* __restrict__ Wbc,  const float* __restrict__ bbc,
              const float* __restrict__ Wuq,  const float* __restrict__ buq,
              const float* __restrict__ Wue,  const float* __restrict__ bue,
              const float* __restrict__ ln_g, const float* __restrict__ ln_b,
              const float* __restrict__ Wo,   const float* __restrict__ bo,
              float* __restrict__ out)
{
    const int b = blockIdx.x >> 3;
    const int s = blockIdx.x & 7;          // 64-wide output slice
    const int t = threadIdx.x;

    __shared__ float shS[kBD];
    __shared__ float shB[kD];
    __shared__ float shMs[kBD];
    __shared__ float shN[kD];
    __shared__ float redT[4][kBD];
    __shared__ float redQ[4][kBD];
    __shared__ float redLN[8];
    __shared__ float s_mu, s_rs;

    if (t < kBD) shS[t] = S[b * kBD + t];
    __syncthreads();

    // Bsum[d] = sum_j S[j]*Wbc[d,j] + n*bbc[d]
    for (int d = t; d < kD; d += 256) {
        const float4* wr = (const float4*)(Wbc + d * kBD);
        float acc = 0.f;
        #pragma unroll
        for (int q4 = 0; q4 < 16; ++q4) {
            float4 w = wr[q4];
            acc += w.x * shS[q4*4+0] + w.y * shS[q4*4+1]
                 + w.z * shS[q4*4+2] + w.w * shS[q4*4+3];
        }
        shB[d] = acc + (float)kN * bbc[d];
    }
    __syncthreads();

    // t[jj] = Bsum.Wuq[jj,:] + n*buq ; q[jj] = query.Wuq[jj,:] + buq ; ms = q*t
    {
        const int jj = t & 63, qq = t >> 6;
        const float4* wr = (const float4*)(Wuq + jj * kD + qq * 128);
        const float4* qr = (const float4*)(query + b * kD + qq * 128);
        const float4* br = (const float4*)(shB + qq * 128);
        float at = 0.f, aq = 0.f;
        #pragma unroll
        for (int i = 0; i < 32; ++i) {
            float4 w = wr[i]; float4 bb = br[i]; float4 qv = qr[i];
            at += w.x*bb.x + w.y*bb.y + w.z*bb.z + w.w*bb.w;
            aq += w.x*qv.x + w.y*qv.y + w.z*qv.z + w.w*qv.w;
        }
        redT[qq][jj] = at; redQ[qq][jj] = aq;
    }
    __syncthreads();
    if (t < kBD) {
        float tv = redT[0][t] + redT[1][t] + redT[2][t] + redT[3][t] + (float)kN * buq[t];
        float qv = redQ[0][t] + redQ[1][t] + redQ[2][t] + redQ[3][t] + buq[t];
        shMs[t] = tv * qv;
    }
    __syncthreads();

    // ext[d] -> ret -> LN stats
    float lsum = 0.f, lsq = 0.f;
    for (int d = t; d < kD; d += 256) {
        const float4* wr = (const float4*)(Wue + d * kBD);
        float acc = 0.f;
        #pragma unroll
        for (int q4 = 0; q4 < 16; ++q4) {
            float4 w = wr[q4];
            acc += w.x * shMs[q4*4+0] + w.y * shMs[q4*4+1]
                 + w.z * shMs[q4*4+2] + w.w * shMs[q4*4+3];
        }
        float ret = (acc + (float)kN * bue[d]) * (1.0f / 64.0f);
        shN[d] = ret;
        lsum += ret; lsq += ret * ret;
    }
    #pragma unroll
    for (int m = 1; m < 64; m <<= 1) {
        lsum += __shfl_xor(lsum, m);
        lsq  += __shfl_xor(lsq, m);
    }
    if ((t & 63) == 0) { redLN[t >> 6] = lsum; redLN[4 + (t >> 6)] = lsq; }
    __syncthreads();
    if (t == 0) {
        float s0 = redLN[0] + redLN[1] + redLN[2] + redLN[3];
        float s1 = redLN[4] + redLN[5] + redLN[6] + redLN[7];
        float mu = s0 / (float)kD;
        float var = s1 / (float)kD - mu * mu;
        s_mu = mu;
        s_rs = rsqrtf(var + 1e-5f);
    }
    __syncthreads();
    {
        float mu = s_mu, rs = s_rs;
        for (int d = t; d < kD; d += 256)
            shN[d] = (shN[d] - mu) * rs * ln_g[d] + ln_b[d];
    }
    __syncthreads();

    // out slice: d = s*64 + t/4, quarter q = t&3 over the 512-dot
    {
        const int d = s * 64 + (t >> 2);
        const int q = t & 3;
        const float4* wr = (const float4*)(Wo + d * kD + q * 128);
        const float4* nr = (const float4*)(shN + q * 128);
        float acc = 0.f;
        #pragma unroll
        for (int i = 0; i < 32; ++i) {
            float4 w = wr[i]; float4 nv = nr[i];
            acc += w.x*nv.x + w.y*nv.y + w.z*nv.z + w.w*nv.w;
        }
        acc += __shfl_xor(acc, 1);
        acc += __shfl_xor(acc, 2);
        if (q == 0) out[b * kD + d] = acc + bo[d];
    }
}

extern "C" void kernel_launch(void* const* d_in, const int* in_sizes, int n_in,
                              void* d_out, int out_size, void* d_ws, size_t ws_size,
                              hipStream_t stream) {
    const float* keys   = (const float*)d_in[0];
    const float* values = (const float*)d_in[1];
    const float* query  = (const float*)d_in[2];
    const float* Wbk    = (const float*)d_in[3];
    const float* bbk    = (const float*)d_in[4];
    const float* Wbv    = (const float*)d_in[5];
    const float* bbv    = (const float*)d_in[6];
    const float* Wbc    = (const float*)d_in[7];
    const float* bbc    = (const float*)d_in[8];
    const float* Wuq    = (const float*)d_in[9];
    const float* buq    = (const float*)d_in[10];
    const float* Wue    = (const float*)d_in[11];
    const float* bue    = (const float*)d_in[12];
    const float* ln_g   = (const float*)d_in[13];
    const float* ln_b   = (const float*)d_in[14];
    const float* Wo     = (const float*)d_in[15];
    const float* bo     = (const float*)d_in[16];

    // ws layout: S[8][64] f32 (2 KB), wsk (64 KB), wsv (64 KB)
    float*  Sacc = (float*)d_ws;
    __bf16* wsk  = (__bf16*)((char*)d_ws + 2048);
    __bf16* wsv  = wsk + kBD * kD;
    float*  out  = (float*)d_out;

    lbm_prep<<<dim3(33), dim3(256), 0, stream>>>(Wbk, Wbv, wsk, wsv, Sacc);

    const int nblocks = (kB * kN) / 128;   // 256 blocks x 512 threads = 1 block/CU
    lbm_bind<<<dim3(nblocks), dim3(512), 0, stream>>>(keys, values, wsk, wsv, bbk, bbv, Sacc);
    lbm_tail<<<dim3(kB * 8), dim3(256), 0, stream>>>(Sacc, query, Wbc, bbc, Wuq, buq,
                                                     Wue, bue, ln_g, ln_b, Wo, bo, out);
}